// Round 1
// 331.450 us; speedup vs baseline: 1.0290x; 1.0290x over previous
//
#include <hip/hip_runtime.h>
#include <hip/hip_bf16.h>
#include <math.h>

// AdaptGNN: B=8, N=2048, D=H=128, 3 layers.
// R5: agg loop uses raw s_barrier + lgkmcnt-only fences (counted vmcnt stays
// in flight across barriers, T3/T4), TQ/TT double-buffered (2 barriers/iter
// instead of 3), grid swizzled so batch == XCD (t/tT L2-resident per XCD).

typedef __attribute__((ext_vector_type(8))) short bf16x8;
typedef __attribute__((ext_vector_type(4))) short bf16x4;
typedef __attribute__((ext_vector_type(4))) float f32x4;

static constexpr int kB = 8, kN = 2048, kH = 128;

static __device__ __forceinline__ ushort bf16bits(float f) {
    __hip_bfloat16 hb = __float2bfloat16(f);
    return *reinterpret_cast<ushort*>(&hb);
}

// LDS-visibility fence + raw barrier: does NOT drain vmcnt, so global
// prefetch loads stay in flight across the barrier (compiler inserts
// counted vmcnt(N) waits at their uses).
#define LDS_BARRIER()                                          \
    do {                                                       \
        asm volatile("s_waitcnt lgkmcnt(0)" ::: "memory");     \
        __builtin_amdgcn_s_barrier();                          \
        __builtin_amdgcn_sched_barrier(0);                     \
    } while (0)

// ---------------- x -> bf16 ----------------
__global__ __launch_bounds__(256) void cvt_bf16_kernel(
    const float* __restrict__ src, ushort* __restrict__ dst, int n4)
{
    int i = blockIdx.x * 256 + threadIdx.x;
    if (i >= n4) return;
    float4 v = ((const float4*)src)[i];
    bf16x4 o;
    o[0] = (short)bf16bits(v.x); o[1] = (short)bf16bits(v.y);
    o[2] = (short)bf16bits(v.z); o[3] = (short)bf16bits(v.w);
    ((bf16x4*)dst)[i] = o;
}

// WT[l][c][d] = bf16(W_l[d][c]) — all 3 layers in one launch
__global__ __launch_bounds__(256) void cvt_wT_kernel(
    const float* __restrict__ W0, const float* __restrict__ W1,
    const float* __restrict__ W2, ushort* __restrict__ WT)
{
    const float* W = blockIdx.y == 0 ? W0 : (blockIdx.y == 1 ? W1 : W2);
    int i = blockIdx.x * 256 + threadIdx.x;  // 0..16383
    int d = i >> 7, c = i & 127;
    WT[(size_t)blockIdx.y * kH * kH + c * kH + d] = bf16bits(W[d * kH + c]);
}

// ---------------- linear (bf16 MFMA) + row-norm + transpose-out ----------------
// 64 rows/block (one batch slice), 256 thr = 4 waves (2r x 2c).
// Outputs: t16[b][q][d], tT16[b][d][q], invn[b][q].
__global__ __launch_bounds__(256) void linear_tr_kernel(
    const ushort* __restrict__ h16, const ushort* __restrict__ WT,
    const float* __restrict__ bias, ushort* __restrict__ t16,
    ushort* __restrict__ tT16, float* __restrict__ invn)
{
    __shared__ float ssb[64][2];
    __shared__ ushort tr[128 * 72];  // [c][p_local], stride 72 (144B, 4-bank rotate)

    const int tid = threadIdx.x, lane = tid & 63, wid = tid >> 6;
    const int wr = wid >> 1, wc = wid & 1, quad = lane >> 4, l16 = lane & 15;
    const int rowbase = blockIdx.x * 64;           // global BN row
    const int b = rowbase / kN, q0 = rowbase % kN; // batch / in-batch row

    f32x4 acc[2][4];
#pragma unroll
    for (int i = 0; i < 2; ++i)
#pragma unroll
        for (int ct = 0; ct < 4; ++ct) acc[i][ct] = (f32x4){0.f, 0.f, 0.f, 0.f};

#pragma unroll
    for (int k = 0; k < 4; ++k) {
        bf16x8 Af[2], Bf[4];
#pragma unroll
        for (int i = 0; i < 2; ++i)
            Af[i] = *(const bf16x8*)&h16[(size_t)(rowbase + wr * 32 + i * 16 + l16) * kH + k * 32 + quad * 8];
#pragma unroll
        for (int ct = 0; ct < 4; ++ct)
            Bf[ct] = *(const bf16x8*)&WT[(size_t)(wc * 64 + ct * 16 + l16) * kH + k * 32 + quad * 8];
#pragma unroll
        for (int i = 0; i < 2; ++i)
#pragma unroll
            for (int ct = 0; ct < 4; ++ct)
                acc[i][ct] = __builtin_amdgcn_mfma_f32_16x16x32_bf16(Af[i], Bf[ct], acc[i][ct], 0, 0, 0);
    }

    float bsr[4];
#pragma unroll
    for (int ct = 0; ct < 4; ++ct) bsr[ct] = bias[wc * 64 + ct * 16 + l16];

    f32x4 ss[2] = {(f32x4){0,0,0,0}, (f32x4){0,0,0,0}};
#pragma unroll
    for (int i = 0; i < 2; ++i)
#pragma unroll
        for (int ct = 0; ct < 4; ++ct)
#pragma unroll
            for (int r = 0; r < 4; ++r) {
                float v = acc[i][ct][r] + bsr[ct];
                acc[i][ct][r] = v;
                ss[i][r] += v * v;
            }
#pragma unroll
    for (int step = 1; step < 16; step <<= 1)
#pragma unroll
        for (int i = 0; i < 2; ++i)
#pragma unroll
            for (int r = 0; r < 4; ++r) ss[i][r] += __shfl_xor(ss[i][r], step);

    if (l16 == 0)
#pragma unroll
        for (int i = 0; i < 2; ++i)
#pragma unroll
            for (int r = 0; r < 4; ++r)
                ssb[wr * 32 + i * 16 + quad * 4 + r][wc] = ss[i][r];
    __syncthreads();
    if (tid < 64) {
        float s2 = ssb[tid][0] + ssb[tid][1];
        invn[rowbase + tid] = 1.f / fmaxf(sqrtf(s2), 1e-12f);
    }

    // t16 stores + tr LDS (transposed) writes
#pragma unroll
    for (int i = 0; i < 2; ++i)
#pragma unroll
        for (int ct = 0; ct < 4; ++ct)
#pragma unroll
            for (int r = 0; r < 4; ++r) {
                const int pl = wr * 32 + i * 16 + quad * 4 + r;
                const int c = wc * 64 + ct * 16 + l16;
                ushort bits = bf16bits(acc[i][ct][r]);
                t16[(size_t)(rowbase + pl) * kH + c] = bits;
                tr[c * 72 + pl] = bits;
            }
    __syncthreads();

    // coalesced tT writeout: 128 c-rows x 64 q
    ushort* tTb = tT16 + (size_t)b * kH * kN;
#pragma unroll
    for (int it = 0; it < 4; ++it) {
        int idx = tid + 256 * it;           // 0..1023
        int c = idx >> 3, ch = idx & 7;
        bf16x8 v = *(const bf16x8*)&tr[c * 72 + ch * 8];
        *(bf16x8*)&tTb[(size_t)c * kN + q0 + ch * 8] = v;
    }
}

// ---------------- fused MFMA aggregation (LDS-staged, counted-vmcnt pipeline) ----------------
// 1024 thr = 16 waves (4 wp x 4 wq); P-tile 64, q-tile 64.
// grid = (batch, ptile): linear block id % 8 == batch -> batch pinned to one XCD
// (t/tT working set per XCD = 1 MB, L2-resident).
// Loop: publish(dbuf) -> BAR -> prefetch issue -> S-phase -> BAR -> O-phase.
// Raw barriers never drain vmcnt: prefetch (rQ,rT,ew,invQ = 7 loads) has a
// full iteration (~S+O) in flight before its first use at next publish.
__global__ __launch_bounds__(1024, 4) void agg_kernel(
    const ushort* __restrict__ t, const ushort* __restrict__ tT,
    const float* __restrict__ invn, const float* __restrict__ ew,
    ushort* __restrict__ hout, float* __restrict__ fout, int last)
{
    __shared__ ushort TQ[2][64 * 136];   // [q][d]  272B stride -> 2-way (free)
    __shared__ ushort TT[2][128 * 72];   // [c][q]  144B stride -> 2-way
    __shared__ ushort Spm[64 * 72];      // [p][q]  144B stride -> 2-way
    __shared__ float invPs[64];

    const int b = blockIdx.x, pbase = blockIdx.y * 64;
    const int tid = threadIdx.x, lane = tid & 63, wid = tid >> 6;
    const int wp = wid >> 2, wq = wid & 3, quad = lane >> 4, l16 = lane & 15;

    const ushort* tb  = t  + (size_t)b * kN * kH;
    const ushort* tTb = tT + (size_t)b * kH * kN;
    const float*  ewb = ew + (size_t)b * kN * kN;
    const float*  invb = invn + b * kN;

    if (tid < 64) invPs[tid] = invb[pbase + tid];

    // A-frags for this wave's 16 P-rows (held all kernel; 8 scattered loads, one-time)
    bf16x8 Af[4];
#pragma unroll
    for (int k = 0; k < 4; ++k)
        Af[k] = *(const bf16x8*)&tb[(size_t)(pbase + wp * 16 + l16) * kH + k * 32 + quad * 8];

    // staging thread map (coalesced): tQ 64x128 (16 thr/row), tT 128x64 (8 thr/row)
    const int sqRow = tid >> 4, sqCh = tid & 15;
    const int stRow = tid >> 3, stCh = tid & 7;
    bf16x8 rQ = *(const bf16x8*)&tb[(size_t)sqRow * kH + sqCh * 8];
    bf16x8 rT = *(const bf16x8*)&tTb[(size_t)stRow * kN + stCh * 8];

    const int ewRow = pbase + wp * 16 + quad * 4;
    float ewc[4], invQc;
    {
        const int qc = wq * 16 + l16;
        invQc = invb[qc];
#pragma unroll
        for (int r = 0; r < 4; ++r) ewc[r] = ewb[(size_t)(ewRow + r) * kN + qc];
    }

    LDS_BARRIER();  // invPs visible (global loads above stay in flight)
    float invPr[4];
#pragma unroll
    for (int r = 0; r < 4; ++r) invPr[r] = invPs[wp * 16 + quad * 4 + r];

    f32x4 oacc[2] = {(f32x4){0,0,0,0}, (f32x4){0,0,0,0}};

    for (int qt = 0; qt < kN / 64; ++qt) {
        const int s = qt & 1;

        // [A] publish staged tile into buffer s (compiler waits counted vmcnt for rQ/rT)
        *(bf16x8*)&TQ[s][sqRow * 136 + sqCh * 8] = rQ;
        *(bf16x8*)&TT[s][stRow * 72 + stCh * 8]  = rT;
        LDS_BARRIER();  // [B] publish visible; prior-iter reads of buf s^1 were
                        // drained by each wave's own lgkmcnt(0) at its last fence

        // [C] prefetch next tile (7 global loads; in flight across both barriers)
        float ewn[4] = {0.f, 0.f, 0.f, 0.f};
        float invQn = 0.f;
        if (qt + 1 < kN / 64) {
            const int qb2 = (qt + 1) * 64;
            rQ = *(const bf16x8*)&tb[(size_t)(qb2 + sqRow) * kH + sqCh * 8];
            rT = *(const bf16x8*)&tTb[(size_t)stRow * kN + qb2 + stCh * 8];
            const int qc = qb2 + wq * 16 + l16;
            invQn = invb[qc];
#pragma unroll
            for (int r = 0; r < 4; ++r) ewn[r] = ewb[(size_t)(ewRow + r) * kN + qc];
        }

        // [D] S-phase: dacc = tP(16) . tQ(16)^T over d=128
        f32x4 dacc = (f32x4){0.f, 0.f, 0.f, 0.f};
#pragma unroll
        for (int k = 0; k < 4; ++k) {
            bf16x8 Bf = *(const bf16x8*)&TQ[s][(wq * 16 + l16) * 136 + k * 32 + quad * 8];
            dacc = __builtin_amdgcn_mfma_f32_16x16x32_bf16(Af[k], Bf, dacc, 0, 0, 0);
        }
        // S' = dacc * ew * invQ -> bf16 -> Spm  (C-layout: row p=quad*4+r, col q=l16)
#pragma unroll
        for (int r = 0; r < 4; ++r)
            Spm[(wp * 16 + quad * 4 + r) * 72 + wq * 16 + l16] = bf16bits(dacc[r] * ewc[r] * invQc);
        LDS_BARRIER();  // [E] Spm visible

        // [F] O-phase: oacc += S'[16p x 64q] @ t[64q x 32c]
#pragma unroll
        for (int k = 0; k < 2; ++k) {
            bf16x8 Sa = *(const bf16x8*)&Spm[(wp * 16 + l16) * 72 + k * 32 + quad * 8];
#pragma unroll
            for (int ct = 0; ct < 2; ++ct) {
                bf16x8 Bb = *(const bf16x8*)&TT[s][(wq * 32 + ct * 16 + l16) * 72 + k * 32 + quad * 8];
                oacc[ct] = __builtin_amdgcn_mfma_f32_16x16x32_bf16(Sa, Bb, oacc[ct], 0, 0, 0);
            }
        }
        // no trailing barrier: next publish targets buffer s^1; re-publish of
        // buffer s is 2 barriers away, and every wave fences lgkmcnt(0) at [A].

#pragma unroll
        for (int r = 0; r < 4; ++r) ewc[r] = ewn[r];
        invQc = invQn;
    }

    // store: O * invP (+relu -> bf16 h, or fp32 final)
#pragma unroll
    for (int ct = 0; ct < 2; ++ct)
#pragma unroll
        for (int r = 0; r < 4; ++r) {
            const int p = pbase + wp * 16 + quad * 4 + r;
            const int c = wq * 32 + ct * 16 + l16;
            float v = oacc[ct][r] * invPr[r];
            if (!last) {
                hout[(size_t)b * kN * kH + (size_t)p * kH + c] = bf16bits(fmaxf(v, 0.f));
            } else {
                fout[(size_t)b * kN * kH + (size_t)p * kH + c] = v;
            }
        }
}

extern "C" void kernel_launch(void* const* d_in, const int* in_sizes, int n_in,
                              void* d_out, int out_size, void* d_ws, size_t ws_size,
                              hipStream_t stream) {
    const float* x  = (const float*)d_in[0];
    const float* ew = (const float*)d_in[1];
    const float* W0 = (const float*)d_in[2];
    const float* b0 = (const float*)d_in[3];
    const float* W1 = (const float*)d_in[4];
    const float* b1 = (const float*)d_in[5];
    const float* W2 = (const float*)d_in[6];
    const float* b2 = (const float*)d_in[7];
    const float* bias[3] = {b0, b1, b2};

    const size_t nBNH = (size_t)kB * kN * kH;  // 2M
    ushort* h16  = (ushort*)d_ws;               // [B,N,H] bf16 (x, then relu h)
    ushort* t16  = h16 + nBNH;                  // [B,N,H] bf16 post-linear
    ushort* tT16 = t16 + nBNH;                  // [B,H,N] bf16 transposed
    float*  invn = (float*)(tT16 + nBNH);       // [B,N]
    ushort* WT   = (ushort*)(invn + (size_t)kB * kN);  // 3 x [H,D] bf16
    float*  out  = (float*)d_out;

    cvt_bf16_kernel<<<(int)(nBNH / 4 + 255) / 256, 256, 0, stream>>>(x, h16, (int)(nBNH / 4));
    cvt_wT_kernel<<<dim3(64, 3), 256, 0, stream>>>(W0, W1, W2, WT);

    for (int layer = 0; layer < 3; ++layer) {
        linear_tr_kernel<<<kB * kN / 64, 256, 0, stream>>>(
            h16, WT + (size_t)layer * kH * kH, bias[layer], t16, tT16, invn);
        agg_kernel<<<dim3(kB, kN / 64), 1024, 0, stream>>>(
            t16, tT16, invn, ew, h16, out, layer == 2 ? 1 : 0);
    }
}

// Round 2
// 324.326 us; speedup vs baseline: 1.0516x; 1.0220x over previous
//
#include <hip/hip_runtime.h>
#include <hip/hip_bf16.h>
#include <math.h>

// AdaptGNN: B=8, N=2048, D=H=128, 3 layers.
// R6: agg LDS tiles rebuilt as power-of-2 strides + XOR swizzle
// (byte ^= (row&7)<<4, m214 recipe) on BOTH write and read — the padded
// strides (272B/144B) were ~8-way conflicted on b128 column-pattern reads.
// R5's raw-barrier + dbuf + counted-vmcnt pipeline kept.

typedef __attribute__((ext_vector_type(8))) short bf16x8;
typedef __attribute__((ext_vector_type(4))) short bf16x4;
typedef __attribute__((ext_vector_type(4))) float f32x4;

static constexpr int kB = 8, kN = 2048, kH = 128;

static __device__ __forceinline__ ushort bf16bits(float f) {
    __hip_bfloat16 hb = __float2bfloat16(f);
    return *reinterpret_cast<ushort*>(&hb);
}

// LDS-visibility fence + raw barrier: does NOT drain vmcnt, so global
// prefetch loads stay in flight across the barrier (compiler inserts
// counted vmcnt(N) waits at their uses).
#define LDS_BARRIER()                                          \
    do {                                                       \
        asm volatile("s_waitcnt lgkmcnt(0)" ::: "memory");     \
        __builtin_amdgcn_s_barrier();                          \
        __builtin_amdgcn_sched_barrier(0);                     \
    } while (0)

// ---------------- x -> bf16 ----------------
__global__ __launch_bounds__(256) void cvt_bf16_kernel(
    const float* __restrict__ src, ushort* __restrict__ dst, int n4)
{
    int i = blockIdx.x * 256 + threadIdx.x;
    if (i >= n4) return;
    float4 v = ((const float4*)src)[i];
    bf16x4 o;
    o[0] = (short)bf16bits(v.x); o[1] = (short)bf16bits(v.y);
    o[2] = (short)bf16bits(v.z); o[3] = (short)bf16bits(v.w);
    ((bf16x4*)dst)[i] = o;
}

// WT[l][c][d] = bf16(W_l[d][c]) — all 3 layers in one launch
__global__ __launch_bounds__(256) void cvt_wT_kernel(
    const float* __restrict__ W0, const float* __restrict__ W1,
    const float* __restrict__ W2, ushort* __restrict__ WT)
{
    const float* W = blockIdx.y == 0 ? W0 : (blockIdx.y == 1 ? W1 : W2);
    int i = blockIdx.x * 256 + threadIdx.x;  // 0..16383
    int d = i >> 7, c = i & 127;
    WT[(size_t)blockIdx.y * kH * kH + c * kH + d] = bf16bits(W[d * kH + c]);
}

// ---------------- linear (bf16 MFMA) + row-norm + transpose-out ----------------
// 64 rows/block (one batch slice), 256 thr = 4 waves (2r x 2c).
// Outputs: t16[b][q][d], tT16[b][d][q], invn[b][q].
__global__ __launch_bounds__(256) void linear_tr_kernel(
    const ushort* __restrict__ h16, const ushort* __restrict__ WT,
    const float* __restrict__ bias, ushort* __restrict__ t16,
    ushort* __restrict__ tT16, float* __restrict__ invn)
{
    __shared__ float ssb[64][2];
    __shared__ ushort tr[128 * 72];  // [c][p_local], stride 144B (+4-bank rotate/row)

    const int tid = threadIdx.x, lane = tid & 63, wid = tid >> 6;
    const int wr = wid >> 1, wc = wid & 1, quad = lane >> 4, l16 = lane & 15;
    const int rowbase = blockIdx.x * 64;           // global BN row
    const int b = rowbase / kN, q0 = rowbase % kN; // batch / in-batch row

    f32x4 acc[2][4];
#pragma unroll
    for (int i = 0; i < 2; ++i)
#pragma unroll
        for (int ct = 0; ct < 4; ++ct) acc[i][ct] = (f32x4){0.f, 0.f, 0.f, 0.f};

#pragma unroll
    for (int k = 0; k < 4; ++k) {
        bf16x8 Af[2], Bf[4];
#pragma unroll
        for (int i = 0; i < 2; ++i)
            Af[i] = *(const bf16x8*)&h16[(size_t)(rowbase + wr * 32 + i * 16 + l16) * kH + k * 32 + quad * 8];
#pragma unroll
        for (int ct = 0; ct < 4; ++ct)
            Bf[ct] = *(const bf16x8*)&WT[(size_t)(wc * 64 + ct * 16 + l16) * kH + k * 32 + quad * 8];
#pragma unroll
        for (int i = 0; i < 2; ++i)
#pragma unroll
            for (int ct = 0; ct < 4; ++ct)
                acc[i][ct] = __builtin_amdgcn_mfma_f32_16x16x32_bf16(Af[i], Bf[ct], acc[i][ct], 0, 0, 0);
    }

    float bsr[4];
#pragma unroll
    for (int ct = 0; ct < 4; ++ct) bsr[ct] = bias[wc * 64 + ct * 16 + l16];

    f32x4 ss[2] = {(f32x4){0,0,0,0}, (f32x4){0,0,0,0}};
#pragma unroll
    for (int i = 0; i < 2; ++i)
#pragma unroll
        for (int ct = 0; ct < 4; ++ct)
#pragma unroll
            for (int r = 0; r < 4; ++r) {
                float v = acc[i][ct][r] + bsr[ct];
                acc[i][ct][r] = v;
                ss[i][r] += v * v;
            }
#pragma unroll
    for (int step = 1; step < 16; step <<= 1)
#pragma unroll
        for (int i = 0; i < 2; ++i)
#pragma unroll
            for (int r = 0; r < 4; ++r) ss[i][r] += __shfl_xor(ss[i][r], step);

    if (l16 == 0)
#pragma unroll
        for (int i = 0; i < 2; ++i)
#pragma unroll
            for (int r = 0; r < 4; ++r)
                ssb[wr * 32 + i * 16 + quad * 4 + r][wc] = ss[i][r];
    __syncthreads();
    if (tid < 64) {
        float s2 = ssb[tid][0] + ssb[tid][1];
        invn[rowbase + tid] = 1.f / fmaxf(sqrtf(s2), 1e-12f);
    }

    // t16 stores + tr LDS (transposed) writes
#pragma unroll
    for (int i = 0; i < 2; ++i)
#pragma unroll
        for (int ct = 0; ct < 4; ++ct)
#pragma unroll
            for (int r = 0; r < 4; ++r) {
                const int pl = wr * 32 + i * 16 + quad * 4 + r;
                const int c = wc * 64 + ct * 16 + l16;
                ushort bits = bf16bits(acc[i][ct][r]);
                t16[(size_t)(rowbase + pl) * kH + c] = bits;
                tr[c * 72 + pl] = bits;
            }
    __syncthreads();

    // coalesced tT writeout: 128 c-rows x 64 q
    ushort* tTb = tT16 + (size_t)b * kH * kN;
#pragma unroll
    for (int it = 0; it < 4; ++it) {
        int idx = tid + 256 * it;           // 0..1023
        int c = idx >> 3, ch = idx & 7;
        bf16x8 v = *(const bf16x8*)&tr[c * 72 + ch * 8];
        *(bf16x8*)&tTb[(size_t)c * kN + q0 + ch * 8] = v;
    }
}

// ---------------- fused MFMA aggregation (LDS-staged, swizzled, pipelined) ----------------
// 1024 thr = 16 waves (4 wp x 4 wq); P-tile 64, q-tile 64.
// grid = (batch, ptile): linear id % 8 == batch -> batch pinned to one XCD.
// All LDS tiles: power-of-2 row stride + XOR swizzle byte^=((row&7)<<4),
// applied identically on write and read (involution, reg-staged writes).
__global__ __launch_bounds__(1024, 4) void agg_kernel(
    const ushort* __restrict__ t, const ushort* __restrict__ tT,
    const float* __restrict__ invn, const float* __restrict__ ew,
    ushort* __restrict__ hout, float* __restrict__ fout, int last)
{
    __shared__ char TQ[2][64 * 256];    // [q][d] bf16, 256B rows, swizzled
    __shared__ char TT[2][128 * 128];   // [c][q] bf16, 128B rows, swizzled
    __shared__ char Spm[64 * 128];      // [p][q] bf16, 128B rows, swizzled
    __shared__ float invPs[64];

    const int b = blockIdx.x, pbase = blockIdx.y * 64;
    const int tid = threadIdx.x, lane = tid & 63, wid = tid >> 6;
    const int wp = wid >> 2, wq = wid & 3, quad = lane >> 4, l16 = lane & 15;

    const ushort* tb  = t  + (size_t)b * kN * kH;
    const ushort* tTb = tT + (size_t)b * kH * kN;
    const float*  ewb = ew + (size_t)b * kN * kN;
    const float*  invb = invn + b * kN;

    if (tid < 64) invPs[tid] = invb[pbase + tid];

    // A-frags for this wave's 16 P-rows (held all kernel)
    bf16x8 Af[4];
#pragma unroll
    for (int k = 0; k < 4; ++k)
        Af[k] = *(const bf16x8*)&tb[(size_t)(pbase + wp * 16 + l16) * kH + k * 32 + quad * 8];

    // staging thread map (coalesced): tQ 64x128 (16 thr/row), tT 128x64 (8 thr/row)
    const int sqRow = tid >> 4, sqCh = tid & 15;
    const int stRow = tid >> 3, stCh = tid & 7;
    // swizzled LDS byte offsets (constant per thread)
    const int sqOff = sqRow * 256 + ((sqCh * 16) ^ ((sqRow & 7) << 4));
    const int stOff = stRow * 128 + ((stCh * 16) ^ ((stRow & 7) << 4));
    bf16x8 rQ = *(const bf16x8*)&tb[(size_t)sqRow * kH + sqCh * 8];
    bf16x8 rT = *(const bf16x8*)&tTb[(size_t)stRow * kN + stCh * 8];

    const int ewRow = pbase + wp * 16 + quad * 4;
    float ewc[4], invQc;
    {
        const int qc = wq * 16 + l16;
        invQc = invb[qc];
#pragma unroll
        for (int r = 0; r < 4; ++r) ewc[r] = ewb[(size_t)(ewRow + r) * kN + qc];
    }

    LDS_BARRIER();  // invPs visible (global loads above stay in flight)
    float invPr[4];
#pragma unroll
    for (int r = 0; r < 4; ++r) invPr[r] = invPs[wp * 16 + quad * 4 + r];

    // S-phase read offsets (TQ): row = wq*16+l16, chunk = k*64 + quad*16
    const int sRow = wq * 16 + l16;
    const int sSwz = (sRow & 7) << 4;
    // Spm write: row = wp*16+quad*4+r, byte col = (wq*16+l16)*2
    // Spm read (O-phase A): row = wp*16+l16
    const int paRow = wp * 16 + l16;
    const int paSwz = (paRow & 7) << 4;
    // O-phase B read (TT): row = wq*32 + ct*16 + l16

    f32x4 oacc[2] = {(f32x4){0,0,0,0}, (f32x4){0,0,0,0}};

    for (int qt = 0; qt < kN / 64; ++qt) {
        const int s = qt & 1;

        // [A] publish staged tile into buffer s
        *(bf16x8*)&TQ[s][sqOff] = rQ;
        *(bf16x8*)&TT[s][stOff] = rT;
        LDS_BARRIER();  // [B]

        // [C] prefetch next tile (7 global loads; in flight across barriers)
        float ewn[4] = {0.f, 0.f, 0.f, 0.f};
        float invQn = 0.f;
        if (qt + 1 < kN / 64) {
            const int qb2 = (qt + 1) * 64;
            rQ = *(const bf16x8*)&tb[(size_t)(qb2 + sqRow) * kH + sqCh * 8];
            rT = *(const bf16x8*)&tTb[(size_t)stRow * kN + qb2 + stCh * 8];
            const int qc = qb2 + wq * 16 + l16;
            invQn = invb[qc];
#pragma unroll
            for (int r = 0; r < 4; ++r) ewn[r] = ewb[(size_t)(ewRow + r) * kN + qc];
        }

        // [D] S-phase: dacc = tP(16) . tQ(16)^T over d=128 (2 parallel chains)
        f32x4 da0 = (f32x4){0.f, 0.f, 0.f, 0.f};
        f32x4 da1 = (f32x4){0.f, 0.f, 0.f, 0.f};
#pragma unroll
        for (int k = 0; k < 4; k += 2) {
            bf16x8 Bf0 = *(const bf16x8*)&TQ[s][sRow * 256 + ((k * 64 + quad * 16) ^ sSwz)];
            bf16x8 Bf1 = *(const bf16x8*)&TQ[s][sRow * 256 + (((k + 1) * 64 + quad * 16) ^ sSwz)];
            da0 = __builtin_amdgcn_mfma_f32_16x16x32_bf16(Af[k], Bf0, da0, 0, 0, 0);
            da1 = __builtin_amdgcn_mfma_f32_16x16x32_bf16(Af[k + 1], Bf1, da1, 0, 0, 0);
        }
        // S' = dacc * ew * invQ -> bf16 -> Spm (C-layout: row p=quad*4+r, col q=l16)
#pragma unroll
        for (int r = 0; r < 4; ++r) {
            const int prow = wp * 16 + quad * 4 + r;
            const int poff = prow * 128 + (((wq * 16 + l16) * 2) ^ ((prow & 7) << 4));
            *(ushort*)&Spm[poff] = bf16bits((da0[r] + da1[r]) * ewc[r] * invQc);
        }
        LDS_BARRIER();  // [E] Spm visible

        // [F] O-phase: oacc += S'[16p x 64q] @ t[64q x 32c]
#pragma unroll
        for (int k = 0; k < 2; ++k) {
            bf16x8 Sa = *(const bf16x8*)&Spm[paRow * 128 + ((k * 64 + quad * 16) ^ paSwz)];
#pragma unroll
            for (int ct = 0; ct < 2; ++ct) {
                const int bRow = wq * 32 + ct * 16 + l16;
                bf16x8 Bb = *(const bf16x8*)&TT[s][bRow * 128 + ((k * 64 + quad * 16) ^ ((bRow & 7) << 4))];
                oacc[ct] = __builtin_amdgcn_mfma_f32_16x16x32_bf16(Sa, Bb, oacc[ct], 0, 0, 0);
            }
        }
        // no trailing barrier: next publish targets buffer s^1; re-publish of
        // buffer s is 2 barriers away; every wave fences lgkmcnt(0) at [A]/[E].

#pragma unroll
        for (int r = 0; r < 4; ++r) ewc[r] = ewn[r];
        invQc = invQn;
    }

    // store: O * invP (+relu -> bf16 h, or fp32 final)
#pragma unroll
    for (int ct = 0; ct < 2; ++ct)
#pragma unroll
        for (int r = 0; r < 4; ++r) {
            const int p = pbase + wp * 16 + quad * 4 + r;
            const int c = wq * 32 + ct * 16 + l16;
            float v = oacc[ct][r] * invPr[r];
            if (!last) {
                hout[(size_t)b * kN * kH + (size_t)p * kH + c] = bf16bits(fmaxf(v, 0.f));
            } else {
                fout[(size_t)b * kN * kH + (size_t)p * kH + c] = v;
            }
        }
}

extern "C" void kernel_launch(void* const* d_in, const int* in_sizes, int n_in,
                              void* d_out, int out_size, void* d_ws, size_t ws_size,
                              hipStream_t stream) {
    const float* x  = (const float*)d_in[0];
    const float* ew = (const float*)d_in[1];
    const float* W0 = (const float*)d_in[2];
    const float* b0 = (const float*)d_in[3];
    const float* W1 = (const float*)d_in[4];
    const float* b1 = (const float*)d_in[5];
    const float* W2 = (const float*)d_in[6];
    const float* b2 = (const float*)d_in[7];
    const float* bias[3] = {b0, b1, b2};

    const size_t nBNH = (size_t)kB * kN * kH;  // 2M
    ushort* h16  = (ushort*)d_ws;               // [B,N,H] bf16 (x, then relu h)
    ushort* t16  = h16 + nBNH;                  // [B,N,H] bf16 post-linear
    ushort* tT16 = t16 + nBNH;                  // [B,H,N] bf16 transposed
    float*  invn = (float*)(tT16 + nBNH);       // [B,N]
    ushort* WT   = (ushort*)(invn + (size_t)kB * kN);  // 3 x [H,D] bf16
    float*  out  = (float*)d_out;

    cvt_bf16_kernel<<<(int)(nBNH / 4 + 255) / 256, 256, 0, stream>>>(x, h16, (int)(nBNH / 4));
    cvt_wT_kernel<<<dim3(64, 3), 256, 0, stream>>>(W0, W1, W2, WT);

    for (int layer = 0; layer < 3; ++layer) {
        linear_tr_kernel<<<kB * kN / 64, 256, 0, stream>>>(
            h16, WT + (size_t)layer * kH * kH, bias[layer], t16, tT16, invn);
        agg_kernel<<<dim3(kB, kN / 64), 1024, 0, stream>>>(
            t16, tT16, invn, ew, h16, out, layer == 2 ? 1 : 0);
    }
}